// Round 13
// baseline (654.685 us; speedup 1.0000x reference)
//
#include <hip/hip_runtime.h>
#include <hip/hip_bf16.h>

typedef short s8v  __attribute__((ext_vector_type(8)));
typedef float f32x4 __attribute__((ext_vector_type(4)));
typedef unsigned int u32;
typedef u32 u32x4 __attribute__((ext_vector_type(4)));

#define NSLOT 31
#define NBIAS 17

// ---------- bf16 helpers (RNE) ----------
__device__ __forceinline__ unsigned short b16hi(float v) {
  unsigned int u = __float_as_uint(v);
  return (unsigned short)((u + 0x7FFFu + ((u >> 16) & 1u)) >> 16);
}
__device__ __forceinline__ float b16tof(unsigned short h) {
  return __uint_as_float(((unsigned int)h) << 16);
}
__device__ __forceinline__ unsigned short lobits(float w) {
  return b16hi(w - b16tof(b16hi(w)));
}
__device__ __forceinline__ float sp_stable(float v) {
  float ax = __builtin_fabsf(v);
  float e  = __expf(-ax);
  return fmaxf(v, 0.0f) + __logf(1.0f + e);
}

// =====================================================================
// PREP (R12 layout, verified): A-frags for D = W . act^T, biases zeroed
// out of the weight slots; exact-f32 bias table consumed as MFMA C-init.
// lane l: m = l&15, k = 4*(l>>4)+{0..3} (dw0,1) and 16+4*(l>>4)+{0..3} (dw2,3)
// =====================================================================
struct P {
  const float *yW0,*yWs,*yb,*zW0,*zWs,*zb,*tW0,*tWs,*tb;
  const float *x0W,*x0b,*y0W,*y0b,*z0W,*z0b,*t0W,*t0b;
  const float *xWs,*xb,*xsW,*xsb,*xyW,*xyb,*xzW,*xzb,*xtW,*xtb,*fW,*fb;
};

__device__ unsigned short pat15(const float* W, int k, int j, int sp) {
  if (k < 15)           { float v = W[j*15+k];      return b16hi(sp ? sp_stable(v) : v); }
  if (k >= 16 && k < 31){ float v = W[j*15+(k-16)]; return lobits(sp ? sp_stable(v) : v); }
  return 0;
}

__device__ unsigned short wA(int s, int k, int j, const P& p) {
  if (j > 14) return 0;
  if (s == 0) {
    if (k < 8)   return b16hi(sp_stable(p.yW0[j*8+k]));
    if (k < 16)  return lobits(sp_stable(p.yW0[j*8+(k-8)]));
    return 0;
  }
  if (s <= 3)  return pat15(p.yWs + (s-1)*225, k, j, 1);
  if (s == 4) {
    if (k < 8)   return b16hi(p.zW0[j*8+k]);
    if (k < 16)  return lobits(p.zW0[j*8+(k-8)]);
    return 0;
  }
  if (s <= 7)  return pat15(p.zWs + (s-5)*225, k, j, 0);
  if (s == 8) {
    if (k < 4)   return b16hi(sp_stable(p.tW0[j*4+k]));
    if (k < 8)   return lobits(sp_stable(p.tW0[j*4+(k-4)]));
    return 0;
  }
  if (s <= 11) return pat15(p.tWs + (s-9)*225, k, j, 1);
  if (s == 12) {
    if (k < 16) return b16hi(p.x0W[j*16+k]);
    return lobits(p.x0W[j*16+(k-16)]);
  }
  if (s == 13) {
    if (k < 8)  return b16hi(sp_stable(p.y0W[j*8+k]));
    if (k < 16) return b16hi(p.z0W[j*8+(k-8)]);
    if (k < 24) return lobits(sp_stable(p.y0W[j*8+(k-16)]));
    return lobits(p.z0W[j*8+(k-24)]);
  }
  if (s == 14) {
    if (k < 4)  return b16hi(sp_stable(p.t0W[j*4+k]));
    if (k < 8)  return lobits(sp_stable(p.t0W[j*4+(k-4)]));
    return 0;
  }
  if (s <= 29) {
    int i = (s-15)/5, r = (s-15)%5;
    if (r == 0) return pat15(p.xWs + i*225, k, j, 1);
    if (r == 1) {
      const float* W = p.xsW + i*240;
      if (k < 16) return b16hi(W[j*16+k]);
      return lobits(W[j*16+(k-16)]);
    }
    if (r == 2) return pat15(p.xyW + i*225, k, j, 1);
    if (r == 3) return pat15(p.xzW + i*225, k, j, 0);
    return pat15(p.xtW + i*225, k, j, 1);
  }
  return pat15(p.fW, k, j, 0);   // s == 30
}

__global__ void prep_kernel(P p, u32* Abuf, float* biasb) {
  const int tid = blockIdx.x * blockDim.x + threadIdx.x;
  const int str = gridDim.x * blockDim.x;
  for (int idx = tid; idx < NSLOT*256; idx += str) {
    int s = idx >> 8, rem = idx & 255, l = rem >> 2, d = rem & 3;
    int g = l >> 4, j = l & 15;
    int kb = (d < 2) ? (4*g + 2*d) : (16 + 4*g + 2*(d-2));
    u32 v0 = wA(s, kb,   j, p);
    u32 v1 = wA(s, kb+1, j, p);
    Abuf[idx] = v0 | (v1 << 16);
  }
  // bias table: [set][16] f32: 0-3 yb, 4-7 zb, 8-11 tb, 12 xfb,
  // 13-15 xlb, 16 fb; channel 15 = 0 pad.
  for (int idx = tid; idx < NBIAS*16; idx += str) {
    int b = idx >> 4, n = idx & 15;
    float v = 0.f;
    if (n < 15) {
      if (b < 4)        v = p.yb[b*15 + n];
      else if (b < 8)   v = p.zb[(b-4)*15 + n];
      else if (b < 12)  v = p.tb[(b-8)*15 + n];
      else if (b == 12) v = p.x0b[n] + p.y0b[n] + p.z0b[n] + p.t0b[n];
      else if (b < 16)  { int i = b - 13;
        v = p.xb[i*15+n] + p.xsb[i*15+n] + p.xyb[i*15+n]
          + p.xzb[i*15+n] + p.xtb[i*15+n]; }
      else              v = p.fb[n];
    }
    biasb[idx] = v;
  }
}

// =====================================================================
// MAIN: 512-thread blocks, 8 waves share one LDS weight image; 4 tiles
// per wave with a NON-UNROLLED tile loop (R12 lesson: #pragma unroll let
// the scheduler hoist all 4 tiles' loads -> 300MB scratch spill; unroll 1
// keeps exactly one tile's live state = R11's proven spill-free set).
// Bias via MFMA C-init; pk-f32 act arithmetic around scalar exp2/log/rcp.
// =====================================================================
union FragU { u32x4 u; s8v s; };
__device__ __forceinline__ s8v mkfrag(u32 a, u32 b, u32 c, u32 d) {
  FragU f; f.u = u32x4{a, b, c, d}; return f.s;
}
__device__ __forceinline__ u32 pk(float lo, float hi) {
  union { __hip_bfloat162 h; u32 u; } cv;
  cv.h = __float22bfloat162_rn(float2{lo, hi});
  return cv.u;
}
__device__ __forceinline__ float lo16f(u32 u) { return __uint_as_float(u << 16); }
__device__ __forceinline__ float hi16f(u32 u) { return __uint_as_float(u & 0xFFFF0000u); }

#define MFMA(A,B,C) __builtin_amdgcn_mfma_f32_16x16x32_bf16((A),(B),(C),0,0,0)

__device__ __forceinline__ void act_sp(f32x4 a, u32& h0, u32& h1,
                                       u32& l0, u32& l1) {
  const f32x4 z4 = {0.f, 0.f, 0.f, 0.f};
  f32x4 ax = __builtin_elementwise_abs(a);
  f32x4 mx = __builtin_elementwise_max(a, z4);
  f32x4 nt = ax * -1.442695041f;
  f32x4 e;
  e[0] = __builtin_amdgcn_exp2f(nt[0]); e[1] = __builtin_amdgcn_exp2f(nt[1]);
  e[2] = __builtin_amdgcn_exp2f(nt[2]); e[3] = __builtin_amdgcn_exp2f(nt[3]);
  f32x4 op = e + 1.0f;
  f32x4 lg;
  lg[0] = __builtin_amdgcn_logf(op[0]); lg[1] = __builtin_amdgcn_logf(op[1]);
  lg[2] = __builtin_amdgcn_logf(op[2]); lg[3] = __builtin_amdgcn_logf(op[3]);
  f32x4 v = lg * 0.6931471806f + mx;
  h0 = pk(v[0], v[1]);
  h1 = pk(v[2], v[3]);
  l0 = pk(v[0] - lo16f(h0), v[1] - hi16f(h0));
  l1 = pk(v[2] - lo16f(h1), v[3] - hi16f(h1));
}
__device__ __forceinline__ void act_sig(f32x4 a, u32& d0, u32& d1) {
  f32x4 nt = a * -1.442695041f;
  f32x4 e;
  e[0] = __builtin_amdgcn_exp2f(nt[0]); e[1] = __builtin_amdgcn_exp2f(nt[1]);
  e[2] = __builtin_amdgcn_exp2f(nt[2]); e[3] = __builtin_amdgcn_exp2f(nt[3]);
  f32x4 op = e + 1.0f;
  float r0 = __builtin_amdgcn_rcpf(op[0]), r1 = __builtin_amdgcn_rcpf(op[1]);
  float r2 = __builtin_amdgcn_rcpf(op[2]), r3 = __builtin_amdgcn_rcpf(op[3]);
  d0 = pk(r0, r1);
  d1 = pk(r2, r3);
}

#define NWAVE 8
#define NT 4

__global__ __launch_bounds__(512, 6) void isnn_fwd(
    const float* __restrict__ x0g, const float* __restrict__ y0g,
    const float* __restrict__ z0g, const float* __restrict__ t0g,
    const u32* __restrict__ Abuf, const float* __restrict__ biasg,
    float* __restrict__ outg)
{
  __shared__ u32x4 wlds[NSLOT*64];        // 31 KiB weight frags (block-shared)
  __shared__ float blds[NBIAS*16];        // 1.0625 KiB bias table
  __shared__ float olds[NWAVE][320];      // per-wave out staging (10 KiB)

  const int tid = threadIdx.x;
  for (int i = tid; i < NSLOT*64; i += 512) wlds[i] = ((const u32x4*)Abuf)[i];
  for (int i = tid; i < NBIAS*16; i += 512) blds[i] = biasg[i];
  __syncthreads();

  const int lane = tid & 63;
  const int w    = tid >> 6;
  const int g    = lane >> 4;
  const int c    = lane & 15;

  const char* wbase = (const char*)wlds + lane * 16;
#define AW(s)   (*(const s8v*)(wbase + (s)*1024))
  const char* bbase = (const char*)blds + g * 16;
#define BIAS(s) (*(const f32x4*)(bbase + (s)*64))

  int oidx[4]; bool oon[4];
#pragma unroll
  for (int jj = 0; jj < 4; ++jj) {
    int i = lane + 64*jj;
    oon[jj]  = (i < 240);
    int row  = i / 15, ch = i - row*15;
    oidx[jj] = row*20 + ch;
  }

  const int T0 = (blockIdx.x * NWAVE + w) * NT;

#pragma unroll 1
  for (int it = 0; it < NT; ++it) {
    const int T = T0 + it;

    // ---- inputs (loop NOT unrolled -> loads genuinely in-loop, no spill)
    float4 x4 = ((const float4*)x0g)[(size_t)(T*16 + c)*4 + g];
    float4 y4 = ((const float4*)y0g)[(size_t)(T*16 + c)*2 + (g & 1)];
    float4 z4 = ((const float4*)z0g)[(size_t)(T*16 + c)*2 + (g & 1)];
    float4 t4 = ((const float4*)t0g)[(size_t)(T*16 + c)];

    // ---- build input B-frags
    u32 dx0 = pk(x4.x, x4.y), dx1 = pk(x4.z, x4.w);
    u32 dy0 = pk(y4.x, y4.y), dy1 = pk(y4.z, y4.w);
    u32 dz0 = pk(z4.x, z4.y), dz1 = pk(z4.z, z4.w);
    u32 dt0 = pk(t4.x, t4.y), dt1 = pk(t4.z, t4.w);
    s8v Bx0 = mkfrag(dx0, dx1, dx0, dx1);
    s8v By0 = mkfrag(dy0, dy1, 0u, 0u);
    s8v Bz0 = mkfrag(dz0, dz1, 0u, 0u);
    s8v Bt0 = mkfrag((g < 2) ? dt0 : 0u, (g < 2) ? dt1 : 0u, 0u, 0u);
    u32 syz0 = (g < 2) ? dy0 : dz0, syz1 = (g < 2) ? dy1 : dz1;
    s8v Byz = mkfrag(syz0, syz1, syz0, syz1);

    // ---- towers layer 1 (bias = exact-f32 C-init)
    f32x4 aY = MFMA(AW(0), By0, BIAS(0));
    f32x4 aZ = MFMA(AW(4), Bz0, BIAS(4));
    f32x4 aT = MFMA(AW(8), Bt0, BIAS(8));

    // ---- towers layers 2..4
    u32 yh0, yh1, yl0, yl1, zf0, zf1, tf0, tf1;
#pragma unroll
    for (int l = 0; l < 3; ++l) {
      act_sp(aY, yh0, yh1, yl0, yl1);
      act_sig(aZ, zf0, zf1);
      act_sig(aT, tf0, tf1);
      s8v ay = AW(1+l);
      aY = MFMA(ay, mkfrag(yh0, yh1, yh0, yh1), BIAS(1+l));
      aY = MFMA(ay, mkfrag(yl0, yl1, 0u, 0u), aY);
      aZ = MFMA(AW(5+l), mkfrag(zf0, zf1, zf0, zf1), BIAS(5+l));
      aT = MFMA(AW(9+l), mkfrag(tf0, tf1, tf0, tf1), BIAS(9+l));
    }
    act_sp(aY, yh0, yh1, yl0, yl1);
    act_sig(aZ, zf0, zf1);
    act_sig(aT, tf0, tf1);
    s8v FyH = mkfrag(yh0, yh1, yh0, yh1);
    s8v FyL = mkfrag(yl0, yl1, 0u, 0u);
    s8v Fz  = mkfrag(zf0, zf1, zf0, zf1);
    s8v Ft  = mkfrag(tf0, tf1, tf0, tf1);

    // ---- x first block
    f32x4 aX = MFMA(AW(12), Bx0, BIAS(12));
    aX = MFMA(AW(13), Byz, aX);
    aX = MFMA(AW(14), Bt0, aX);

    // ---- 3 x iterations
    u32 xh0, xh1, xl0, xl1;
#pragma unroll
    for (int i = 0; i < 3; ++i) {
      act_sp(aX, xh0, xh1, xl0, xl1);
      s8v ax = AW(15+5*i);
      aX = MFMA(ax, mkfrag(xh0, xh1, xh0, xh1), BIAS(13+i));
      aX = MFMA(ax, mkfrag(xl0, xl1, 0u, 0u), aX);
      aX = MFMA(AW(16+5*i), Bx0, aX);
      s8v axy = AW(17+5*i);
      aX = MFMA(axy, FyH, aX);
      aX = MFMA(axy, FyL, aX);
      aX = MFMA(AW(18+5*i), Fz, aX);
      aX = MFMA(AW(19+5*i), Ft, aX);
    }

    // ---- final linear
    act_sp(aX, xh0, xh1, xl0, xl1);
    s8v af = AW(30);
    f32x4 aO = MFMA(af, mkfrag(xh0, xh1, xh0, xh1), BIAS(16));
    aO = MFMA(af, mkfrag(xl0, xl1, 0u, 0u), aO);

    // ---- coalesced store via tiny LDS transpose
    *(f32x4*)(&olds[w][c*20 + 4*g]) = aO;
    float* orow = outg + (size_t)T * 240;
#pragma unroll
    for (int jj = 0; jj < 4; ++jj)
      if (oon[jj]) orow[lane + 64*jj] = olds[w][oidx[jj]];
  }
#undef AW
#undef BIAS
}

extern "C" void kernel_launch(void* const* d_in, const int* in_sizes, int n_in,
                              void* d_out, int out_size, void* d_ws, size_t ws_size,
                              hipStream_t stream) {
  P p;
  p.yW0 = (const float*)d_in[4];  p.yWs = (const float*)d_in[5];  p.yb  = (const float*)d_in[6];
  p.zW0 = (const float*)d_in[7];  p.zWs = (const float*)d_in[8];  p.zb  = (const float*)d_in[9];
  p.tW0 = (const float*)d_in[10]; p.tWs = (const float*)d_in[11]; p.tb  = (const float*)d_in[12];
  p.x0W = (const float*)d_in[13]; p.x0b = (const float*)d_in[14];
  p.y0W = (const float*)d_in[15]; p.y0b = (const float*)d_in[16];
  p.z0W = (const float*)d_in[17]; p.z0b = (const float*)d_in[18];
  p.t0W = (const float*)d_in[19]; p.t0b = (const float*)d_in[20];
  p.xWs = (const float*)d_in[21]; p.xb  = (const float*)d_in[22];
  p.xsW = (const float*)d_in[23]; p.xsb = (const float*)d_in[24];
  p.xyW = (const float*)d_in[25]; p.xyb = (const float*)d_in[26];
  p.xzW = (const float*)d_in[27]; p.xzb = (const float*)d_in[28];
  p.xtW = (const float*)d_in[29]; p.xtb = (const float*)d_in[30];
  p.fW  = (const float*)d_in[31]; p.fb  = (const float*)d_in[32];

  u32* Abuf = (u32*)d_ws;
  float* biasb = (float*)(Abuf + NSLOT*256);

  prep_kernel<<<8, 256, 0, stream>>>(p, Abuf, biasb);

  const float* x0 = (const float*)d_in[0];
  const float* y0 = (const float*)d_in[1];
  const float* z0 = (const float*)d_in[2];
  const float* t0 = (const float*)d_in[3];

  const int n = in_sizes[0] / 16;           // 1048576 rows
  const int blocks = n / (NWAVE * 16 * NT); // 8 waves x 4 tiles x 16 rows = 2048
  isnn_fwd<<<blocks, 512, 0, stream>>>(x0, y0, z0, t0, Abuf, biasb, (float*)d_out);
}

// Round 14
// 109.773 us; speedup vs baseline: 5.9640x; 5.9640x over previous
//
#include <hip/hip_runtime.h>
#include <hip/hip_bf16.h>

typedef short s8v  __attribute__((ext_vector_type(8)));
typedef float f32x4 __attribute__((ext_vector_type(4)));
typedef unsigned int u32;
typedef u32 u32x4 __attribute__((ext_vector_type(4)));

#define NSLOT 31
#define NBIAS 17

// ---------- bf16 helpers (RNE) ----------
__device__ __forceinline__ unsigned short b16hi(float v) {
  unsigned int u = __float_as_uint(v);
  return (unsigned short)((u + 0x7FFFu + ((u >> 16) & 1u)) >> 16);
}
__device__ __forceinline__ float b16tof(unsigned short h) {
  return __uint_as_float(((unsigned int)h) << 16);
}
__device__ __forceinline__ unsigned short lobits(float w) {
  return b16hi(w - b16tof(b16hi(w)));
}
__device__ __forceinline__ float sp_stable(float v) {
  float ax = __builtin_fabsf(v);
  float e  = __expf(-ax);
  return fmaxf(v, 0.0f) + __logf(1.0f + e);
}

// =====================================================================
// PREP (R12 layout, verified): A-frags for D = W . act^T, biases zeroed
// out of the weight slots; exact-f32 bias table consumed as MFMA C-init.
// lane l: m = l&15, k = 4*(l>>4)+{0..3} (dw0,1) and 16+4*(l>>4)+{0..3} (dw2,3)
// =====================================================================
struct P {
  const float *yW0,*yWs,*yb,*zW0,*zWs,*zb,*tW0,*tWs,*tb;
  const float *x0W,*x0b,*y0W,*y0b,*z0W,*z0b,*t0W,*t0b;
  const float *xWs,*xb,*xsW,*xsb,*xyW,*xyb,*xzW,*xzb,*xtW,*xtb,*fW,*fb;
};

__device__ unsigned short pat15(const float* W, int k, int j, int sp) {
  if (k < 15)           { float v = W[j*15+k];      return b16hi(sp ? sp_stable(v) : v); }
  if (k >= 16 && k < 31){ float v = W[j*15+(k-16)]; return lobits(sp ? sp_stable(v) : v); }
  return 0;
}

__device__ unsigned short wA(int s, int k, int j, const P& p) {
  if (j > 14) return 0;
  if (s == 0) {
    if (k < 8)   return b16hi(sp_stable(p.yW0[j*8+k]));
    if (k < 16)  return lobits(sp_stable(p.yW0[j*8+(k-8)]));
    return 0;
  }
  if (s <= 3)  return pat15(p.yWs + (s-1)*225, k, j, 1);
  if (s == 4) {
    if (k < 8)   return b16hi(p.zW0[j*8+k]);
    if (k < 16)  return lobits(p.zW0[j*8+(k-8)]);
    return 0;
  }
  if (s <= 7)  return pat15(p.zWs + (s-5)*225, k, j, 0);
  if (s == 8) {
    if (k < 4)   return b16hi(sp_stable(p.tW0[j*4+k]));
    if (k < 8)   return lobits(sp_stable(p.tW0[j*4+(k-4)]));
    return 0;
  }
  if (s <= 11) return pat15(p.tWs + (s-9)*225, k, j, 1);
  if (s == 12) {
    if (k < 16) return b16hi(p.x0W[j*16+k]);
    return lobits(p.x0W[j*16+(k-16)]);
  }
  if (s == 13) {
    if (k < 8)  return b16hi(sp_stable(p.y0W[j*8+k]));
    if (k < 16) return b16hi(p.z0W[j*8+(k-8)]);
    if (k < 24) return lobits(sp_stable(p.y0W[j*8+(k-16)]));
    return lobits(p.z0W[j*8+(k-24)]);
  }
  if (s == 14) {
    if (k < 4)  return b16hi(sp_stable(p.t0W[j*4+k]));
    if (k < 8)  return lobits(sp_stable(p.t0W[j*4+(k-4)]));
    return 0;
  }
  if (s <= 29) {
    int i = (s-15)/5, r = (s-15)%5;
    if (r == 0) return pat15(p.xWs + i*225, k, j, 1);
    if (r == 1) {
      const float* W = p.xsW + i*240;
      if (k < 16) return b16hi(W[j*16+k]);
      return lobits(W[j*16+(k-16)]);
    }
    if (r == 2) return pat15(p.xyW + i*225, k, j, 1);
    if (r == 3) return pat15(p.xzW + i*225, k, j, 0);
    return pat15(p.xtW + i*225, k, j, 1);
  }
  return pat15(p.fW, k, j, 0);   // s == 30
}

__global__ void prep_kernel(P p, u32* Abuf, float* biasb) {
  const int tid = blockIdx.x * blockDim.x + threadIdx.x;
  const int str = gridDim.x * blockDim.x;
  for (int idx = tid; idx < NSLOT*256; idx += str) {
    int s = idx >> 8, rem = idx & 255, l = rem >> 2, d = rem & 3;
    int g = l >> 4, j = l & 15;
    int kb = (d < 2) ? (4*g + 2*d) : (16 + 4*g + 2*(d-2));
    u32 v0 = wA(s, kb,   j, p);
    u32 v1 = wA(s, kb+1, j, p);
    Abuf[idx] = v0 | (v1 << 16);
  }
  // bias table: [set][16] f32: 0-3 yb, 4-7 zb, 8-11 tb, 12 xfb,
  // 13-15 xlb, 16 fb; channel 15 = 0 pad.
  for (int idx = tid; idx < NBIAS*16; idx += str) {
    int b = idx >> 4, n = idx & 15;
    float v = 0.f;
    if (n < 15) {
      if (b < 4)        v = p.yb[b*15 + n];
      else if (b < 8)   v = p.zb[(b-4)*15 + n];
      else if (b < 12)  v = p.tb[(b-8)*15 + n];
      else if (b == 12) v = p.x0b[n] + p.y0b[n] + p.z0b[n] + p.t0b[n];
      else if (b < 16)  { int i = b - 13;
        v = p.xb[i*15+n] + p.xsb[i*15+n] + p.xyb[i*15+n]
          + p.xzb[i*15+n] + p.xtb[i*15+n]; }
      else              v = p.fb[n];
    }
    biasb[idx] = v;
  }
}

// =====================================================================
// MAIN: R11's proven spill-free geometry (ONE tile per wave, straight-
// line body, 512-thread blocks, 8 waves share one LDS weight image,
// (512,6) -> 3 blocks/CU -> 6 waves/SIMD) + R12's instruction diet
// (bias via MFMA C-init -> no masking ops; pk-f32 act arithmetic).
// Ledger: ANY multi-tile loop at this occupancy spills (R10 prefetch /
// R12 unroll-hoist / R13 unroll-1 catastrophic). Do not re-add a loop.
// =====================================================================
union FragU { u32x4 u; s8v s; };
__device__ __forceinline__ s8v mkfrag(u32 a, u32 b, u32 c, u32 d) {
  FragU f; f.u = u32x4{a, b, c, d}; return f.s;
}
__device__ __forceinline__ u32 pk(float lo, float hi) {
  union { __hip_bfloat162 h; u32 u; } cv;
  cv.h = __float22bfloat162_rn(float2{lo, hi});
  return cv.u;
}
__device__ __forceinline__ float lo16f(u32 u) { return __uint_as_float(u << 16); }
__device__ __forceinline__ float hi16f(u32 u) { return __uint_as_float(u & 0xFFFF0000u); }

#define MFMA(A,B,C) __builtin_amdgcn_mfma_f32_16x16x32_bf16((A),(B),(C),0,0,0)

__device__ __forceinline__ void act_sp(f32x4 a, u32& h0, u32& h1,
                                       u32& l0, u32& l1) {
  const f32x4 z4 = {0.f, 0.f, 0.f, 0.f};
  f32x4 ax = __builtin_elementwise_abs(a);
  f32x4 mx = __builtin_elementwise_max(a, z4);
  f32x4 nt = ax * -1.442695041f;
  f32x4 e;
  e[0] = __builtin_amdgcn_exp2f(nt[0]); e[1] = __builtin_amdgcn_exp2f(nt[1]);
  e[2] = __builtin_amdgcn_exp2f(nt[2]); e[3] = __builtin_amdgcn_exp2f(nt[3]);
  f32x4 op = e + 1.0f;
  f32x4 lg;
  lg[0] = __builtin_amdgcn_logf(op[0]); lg[1] = __builtin_amdgcn_logf(op[1]);
  lg[2] = __builtin_amdgcn_logf(op[2]); lg[3] = __builtin_amdgcn_logf(op[3]);
  f32x4 v = lg * 0.6931471806f + mx;
  h0 = pk(v[0], v[1]);
  h1 = pk(v[2], v[3]);
  l0 = pk(v[0] - lo16f(h0), v[1] - hi16f(h0));
  l1 = pk(v[2] - lo16f(h1), v[3] - hi16f(h1));
}
__device__ __forceinline__ void act_sig(f32x4 a, u32& d0, u32& d1) {
  f32x4 nt = a * -1.442695041f;
  f32x4 e;
  e[0] = __builtin_amdgcn_exp2f(nt[0]); e[1] = __builtin_amdgcn_exp2f(nt[1]);
  e[2] = __builtin_amdgcn_exp2f(nt[2]); e[3] = __builtin_amdgcn_exp2f(nt[3]);
  f32x4 op = e + 1.0f;
  float r0 = __builtin_amdgcn_rcpf(op[0]), r1 = __builtin_amdgcn_rcpf(op[1]);
  float r2 = __builtin_amdgcn_rcpf(op[2]), r3 = __builtin_amdgcn_rcpf(op[3]);
  d0 = pk(r0, r1);
  d1 = pk(r2, r3);
}

#define NWAVE 8

__global__ __launch_bounds__(512, 6) void isnn_fwd(
    const float* __restrict__ x0g, const float* __restrict__ y0g,
    const float* __restrict__ z0g, const float* __restrict__ t0g,
    const u32* __restrict__ Abuf, const float* __restrict__ biasg,
    float* __restrict__ outg)
{
  __shared__ u32x4 wlds[NSLOT*64];        // 31 KiB weight frags (block-shared)
  __shared__ float blds[NBIAS*16];        // 1.0625 KiB bias table
  __shared__ float olds[NWAVE][320];      // per-wave out staging (10 KiB)

  const int tid = threadIdx.x;
  for (int i = tid; i < NSLOT*64; i += 512) wlds[i] = ((const u32x4*)Abuf)[i];
  for (int i = tid; i < NBIAS*16; i += 512) blds[i] = biasg[i];
  __syncthreads();

  const int lane = tid & 63;
  const int w    = tid >> 6;
  const int g    = lane >> 4;
  const int c    = lane & 15;

  const char* wbase = (const char*)wlds + lane * 16;
#define AW(s)   (*(const s8v*)(wbase + (s)*1024))
  const char* bbase = (const char*)blds + g * 16;
#define BIAS(s) (*(const f32x4*)(bbase + (s)*64))

  const int T = blockIdx.x * NWAVE + w;    // one 16-row tile per wave

  // ---- inputs: lane (g,c) reads row c; wave reads 1 KiB contiguous
  float4 x4 = ((const float4*)x0g)[(size_t)(T*16 + c)*4 + g];
  float4 y4 = ((const float4*)y0g)[(size_t)(T*16 + c)*2 + (g & 1)];
  float4 z4 = ((const float4*)z0g)[(size_t)(T*16 + c)*2 + (g & 1)];
  float4 t4 = ((const float4*)t0g)[(size_t)(T*16 + c)];

  // ---- build input B-frags
  u32 dx0 = pk(x4.x, x4.y), dx1 = pk(x4.z, x4.w);
  u32 dy0 = pk(y4.x, y4.y), dy1 = pk(y4.z, y4.w);
  u32 dz0 = pk(z4.x, z4.y), dz1 = pk(z4.z, z4.w);
  u32 dt0 = pk(t4.x, t4.y), dt1 = pk(t4.z, t4.w);
  s8v Bx0 = mkfrag(dx0, dx1, dx0, dx1);
  s8v By0 = mkfrag(dy0, dy1, 0u, 0u);
  s8v Bz0 = mkfrag(dz0, dz1, 0u, 0u);
  s8v Bt0 = mkfrag((g < 2) ? dt0 : 0u, (g < 2) ? dt1 : 0u, 0u, 0u);
  u32 syz0 = (g < 2) ? dy0 : dz0, syz1 = (g < 2) ? dy1 : dz1;
  s8v Byz = mkfrag(syz0, syz1, syz0, syz1);

  // ---- towers layer 1 (bias = exact-f32 C-init)
  f32x4 aY = MFMA(AW(0), By0, BIAS(0));
  f32x4 aZ = MFMA(AW(4), Bz0, BIAS(4));
  f32x4 aT = MFMA(AW(8), Bt0, BIAS(8));

  // ---- towers layers 2..4
  u32 yh0, yh1, yl0, yl1, zf0, zf1, tf0, tf1;
#pragma unroll
  for (int l = 0; l < 3; ++l) {
    act_sp(aY, yh0, yh1, yl0, yl1);
    act_sig(aZ, zf0, zf1);
    act_sig(aT, tf0, tf1);
    s8v ay = AW(1+l);
    aY = MFMA(ay, mkfrag(yh0, yh1, yh0, yh1), BIAS(1+l));
    aY = MFMA(ay, mkfrag(yl0, yl1, 0u, 0u), aY);
    aZ = MFMA(AW(5+l), mkfrag(zf0, zf1, zf0, zf1), BIAS(5+l));
    aT = MFMA(AW(9+l), mkfrag(tf0, tf1, tf0, tf1), BIAS(9+l));
  }
  act_sp(aY, yh0, yh1, yl0, yl1);
  act_sig(aZ, zf0, zf1);
  act_sig(aT, tf0, tf1);
  s8v FyH = mkfrag(yh0, yh1, yh0, yh1);
  s8v FyL = mkfrag(yl0, yl1, 0u, 0u);
  s8v Fz  = mkfrag(zf0, zf1, zf0, zf1);
  s8v Ft  = mkfrag(tf0, tf1, tf0, tf1);

  // ---- x first block (xfb bias via C-init of first MFMA)
  f32x4 aX = MFMA(AW(12), Bx0, BIAS(12));
  aX = MFMA(AW(13), Byz, aX);
  aX = MFMA(AW(14), Bt0, aX);

  // ---- 3 x iterations
  u32 xh0, xh1, xl0, xl1;
#pragma unroll
  for (int i = 0; i < 3; ++i) {
    act_sp(aX, xh0, xh1, xl0, xl1);
    s8v ax = AW(15+5*i);
    aX = MFMA(ax, mkfrag(xh0, xh1, xh0, xh1), BIAS(13+i));
    aX = MFMA(ax, mkfrag(xl0, xl1, 0u, 0u), aX);
    aX = MFMA(AW(16+5*i), Bx0, aX);
    s8v axy = AW(17+5*i);
    aX = MFMA(axy, FyH, aX);
    aX = MFMA(axy, FyL, aX);
    aX = MFMA(AW(18+5*i), Fz, aX);
    aX = MFMA(AW(19+5*i), Ft, aX);
  }

  // ---- final linear (fb bias via C-init)
  act_sp(aX, xh0, xh1, xl0, xl1);
  s8v af = AW(30);
  f32x4 aO = MFMA(af, mkfrag(xh0, xh1, xh0, xh1), BIAS(16));
  aO = MFMA(af, mkfrag(xl0, xl1, 0u, 0u), aO);

  // ---- coalesced store via tiny LDS transpose (ch15 slot = dead pad)
  *(f32x4*)(&olds[w][c*20 + 4*g]) = aO;
  float* orow = outg + (size_t)T * 240;
#pragma unroll
  for (int jj = 0; jj < 4; ++jj) {
    int i = lane + 64*jj;
    if (i < 240) {
      int row = i / 15, ch = i - row*15;
      orow[i] = olds[w][row*20 + ch];
    }
  }
#undef AW
#undef BIAS
}

extern "C" void kernel_launch(void* const* d_in, const int* in_sizes, int n_in,
                              void* d_out, int out_size, void* d_ws, size_t ws_size,
                              hipStream_t stream) {
  P p;
  p.yW0 = (const float*)d_in[4];  p.yWs = (const float*)d_in[5];  p.yb  = (const float*)d_in[6];
  p.zW0 = (const float*)d_in[7];  p.zWs = (const float*)d_in[8];  p.zb  = (const float*)d_in[9];
  p.tW0 = (const float*)d_in[10]; p.tWs = (const float*)d_in[11]; p.tb  = (const float*)d_in[12];
  p.x0W = (const float*)d_in[13]; p.x0b = (const float*)d_in[14];
  p.y0W = (const float*)d_in[15]; p.y0b = (const float*)d_in[16];
  p.z0W = (const float*)d_in[17]; p.z0b = (const float*)d_in[18];
  p.t0W = (const float*)d_in[19]; p.t0b = (const float*)d_in[20];
  p.xWs = (const float*)d_in[21]; p.xb  = (const float*)d_in[22];
  p.xsW = (const float*)d_in[23]; p.xsb = (const float*)d_in[24];
  p.xyW = (const float*)d_in[25]; p.xyb = (const float*)d_in[26];
  p.xzW = (const float*)d_in[27]; p.xzb = (const float*)d_in[28];
  p.xtW = (const float*)d_in[29]; p.xtb = (const float*)d_in[30];
  p.fW  = (const float*)d_in[31]; p.fb  = (const float*)d_in[32];

  u32* Abuf = (u32*)d_ws;
  float* biasb = (float*)(Abuf + NSLOT*256);

  prep_kernel<<<8, 256, 0, stream>>>(p, Abuf, biasb);

  const float* x0 = (const float*)d_in[0];
  const float* y0 = (const float*)d_in[1];
  const float* z0 = (const float*)d_in[2];
  const float* t0 = (const float*)d_in[3];

  const int n = in_sizes[0] / 16;          // 1048576 rows
  const int blocks = n / (NWAVE * 16);     // 8 waves x 1 tile x 16 rows = 8192
  isnn_fwd<<<blocks, 512, 0, stream>>>(x0, y0, z0, t0, Abuf, biasb, (float*)d_out);
}